// Round 9
// baseline (176.220 us; speedup 1.0000x reference)
//
#include <hip/hip_runtime.h>

#define IMG_W 2048
#define NUM_NODES 255
#define NLEAF 128
#define DEPTH 7
#define RS 68   // padded LDS row stride (floats); 16B-chunk group = (row+q)%8

// DPP xor-butterfly add over 16-lane groups (VALU pipe).
// Masks {1,2,7,8}: butterfly partners add identical pairs -> all 16 lanes end
// with the same fp sum (commutative), so descent decisions are group-uniform.
template<int CTRL>
__device__ __forceinline__ float dpp_add(float x) {
    int v = __builtin_amdgcn_update_dpp(0, __float_as_int(x), CTRL, 0xF, 0xF, true);
    return x + __int_as_float(v);
}
__device__ __forceinline__ float group16_sum(float x) {
    x = dpp_add<0xB1>(x);   // quad_perm [1,0,3,2]  : xor 1
    x = dpp_add<0x4E>(x);   // quad_perm [2,3,0,1]  : xor 2
    x = dpp_add<0x141>(x);  // row_half_mirror      : xor 7
    x = dpp_add<0x128>(x);  // row_ror:8            : xor 8
    return x;
}

// ---- K1: descend (16 lanes/patch, LDS nodes) + ballot-sweep accumulate ------
// ZERO LDS atomics. 512 blocks x 1024 thr, ~68 KB LDS -> 2 blocks/CU (32 waves).
__global__ __launch_bounds__(1024, 4) void fusedK(const float* __restrict__ img,
                                                  const float* __restrict__ nodes,
                                                  float* __restrict__ leaf_out,
                                                  float* __restrict__ S,
                                                  unsigned* __restrict__ cnt)
{
    __shared__ float nds[NUM_NODES * RS];   // 69360 B; XN (128*RS=8704 fl) overlays after descent
    __shared__ int Lbuf[128];               // leaf index (0..127) per block patch
    float* XN = nds;                        // staged patches (phase 2 overlay)

    const int t = threadIdx.x;
    const int b = blockIdx.x;
    const int g = t >> 4;          // patch-group 0..63
    const int q = t & 15;          // quad within patch (elements 4q..4q+3)
    const int q4 = q * 4;

    // fill node table (padded rows)
    const float4* ng = (const float4*)nodes;
    for (int i = t; i < NUM_NODES * 16; i += 1024) {
        *(float4*)&nds[(i >> 4) * RS + (i & 15) * 4] = ng[i];
    }

    // prefetch both chunks' patch quads (element e=4q+j -> pixel (q>>1, (q&1)*4+j))
    float4 xv[2];
    #pragma unroll
    for (int ch = 0; ch < 2; ++ch) {
        const int p = b * 128 + ch * 64 + g;
        const int r = p >> 8, c = p & 255;
        xv[ch] = *(const float4*)(img + (size_t)(r * 8 + (q >> 1)) * IMG_W + c * 8 + (q & 1) * 4);
    }
    __syncthreads();

    // phase 1: descent (bank-group (row+q)%8 balanced by construction)
    #pragma unroll
    for (int ch = 0; ch < 2; ++ch) {
        const float4 x = xv[ch];
        int cur = 0;
        #pragma unroll
        for (int lvl = 0; lvl < DEPTH; ++lvl) {
            const int c0 = 2 * cur + 1;
            const float* base = &nds[c0 * RS + q4];
            const float4 a  = *(const float4*)(base);        // child c0, quad q
            const float4 bb = *(const float4*)(base + RS);   // child c0+1, quad q
            float s0 = 0.f, s1 = 0.f, d;
            d = a.x  - x.x; s0 = fmaf(d, d, s0);
            d = a.y  - x.y; s0 = fmaf(d, d, s0);
            d = a.z  - x.z; s0 = fmaf(d, d, s0);
            d = a.w  - x.w; s0 = fmaf(d, d, s0);
            d = bb.x - x.x; s1 = fmaf(d, d, s1);
            d = bb.y - x.y; s1 = fmaf(d, d, s1);
            d = bb.z - x.z; s1 = fmaf(d, d, s1);
            d = bb.w - x.w; s1 = fmaf(d, d, s1);
            s0 = group16_sum(s0);
            s1 = group16_sum(s1);
            cur = (s1 < s0) ? (c0 + 1) : c0;   // ref: d1 < d0 picks c1 (strict)
        }
        if (q == 0) {
            leaf_out[b * 128 + ch * 64 + g] = (float)cur;   // leaf node index 127..254
            Lbuf[ch * 64 + g] = cur - 127;
        }
    }
    __syncthreads();                       // all descents done reading nds

    // phase 2: stage patches into XN (plain b128 writes; overlays dead node table)
    #pragma unroll
    for (int ch = 0; ch < 2; ++ch) {
        *(float4*)&XN[(ch * 64 + g) * RS + q4] = xv[ch];
    }
    __syncthreads();

    // ballot sweep: wave w exclusively owns leaf rows 8w..8w+7, held in VGPRs.
    // Lane k = element k. XN reads are same-row lane-strided -> conflict-free.
    const int w = t >> 6, k = t & 63;
    const int L0 = Lbuf[k];          // leaf of patch k
    const int L1 = Lbuf[64 + k];     // leaf of patch 64+k
    float acc[8];
    int   cc[8];
    #pragma unroll
    for (int r = 0; r < 8; ++r) { acc[r] = 0.0f; cc[r] = 0; }

    #pragma unroll
    for (int r = 0; r < 8; ++r) {
        const int row = w * 8 + r;
        unsigned long long m0 = __ballot(L0 == row);
        unsigned long long m1 = __ballot(L1 == row);
        while (m0) {                             // wave-uniform bit loops
            const int p = __ffsll((unsigned long long)m0) - 1;  m0 &= m0 - 1;
            acc[r] += XN[p * RS + k];  cc[r]++;
        }
        while (m1) {
            const int p = 64 + __ffsll((unsigned long long)m1) - 1;  m1 &= m1 - 1;
            acc[r] += XN[p * RS + k];  cc[r]++;
        }
    }

    // flush owned rows (skip empty; lane-distinct global atomics; S pre-zeroed)
    #pragma unroll
    for (int r = 0; r < 8; ++r) {
        if (cc[r] > 0) {
            const int row = w * 8 + r;
            atomicAdd(&S[row * 64 + k], acc[r]);
            if (k == 0) atomicAdd(&cnt[row], (unsigned)cc[r]);
        }
    }
}

// ---------------- K2: node update (254x64x128 contraction) -------------------
__global__ __launch_bounds__(256) void updateK(const float* __restrict__ nodes,
                                               const float* __restrict__ S,
                                               const unsigned* __restrict__ cnt,
                                               float* __restrict__ out)
{
    const int gid = blockIdx.x * 256 + threadIdx.x;
    if (gid >= NUM_NODES * 64) return;
    const int n = gid >> 6, k = gid & 63;
    const float nd = nodes[gid];
    if (n == 0) { out[gid] = nd; return; }

    const int pos = n + 1;                 // 1-based heap index
    const int Ln = 31 - __clz(pos);        // node level, 1..7
    float su = 0.f, sc = 0.f;
    #pragma unroll 8
    for (int L = 0; L < NLEAF; ++L) {
        const int a = (128 + L) >> (7 - Ln);   // leaf's ancestor at level Ln
        const int x = pos ^ a;
        const int state = (x == 0) ? Ln : (Ln - (31 - __clz(x)) - 1);
        const float lr = 0.3f * ((float)(1 << state) * (1.0f / 128.0f));
        su = fmaf(lr, S[L * 64 + k], su);
        sc = fmaf(lr, (float)cnt[L], sc);
    }
    const float invP = 1.0f / 65536.0f;
    out[gid] = nd + su * invP - (sc * invP) * nd;
}

extern "C" void kernel_launch(void* const* d_in, const int* in_sizes, int n_in,
                              void* d_out, int out_size, void* d_ws, size_t ws_size,
                              hipStream_t stream)
{
    const float* img   = (const float*)d_in[0];   // 2048*2048 f32
    const float* nodes = (const float*)d_in[1];   // 255*64 f32

    float* out_nodes = (float*)d_out;                 // 255*64
    float* out_leaf  = out_nodes + NUM_NODES * 64;    // 65536 (leaf index as f32)

    float*    S   = (float*)d_ws;                     // 128*64 f32
    unsigned* cnt = (unsigned*)(S + NLEAF * 64);      // 128 u32

    hipMemsetAsync(d_ws, 0, (NLEAF * 64) * sizeof(float) + NLEAF * sizeof(unsigned), stream);
    fusedK<<<512, 1024, 0, stream>>>(img, nodes, out_leaf, S, cnt);
    updateK<<<64, 256, 0, stream>>>(nodes, S, cnt, out_nodes);
}

// Round 10
// 108.545 us; speedup vs baseline: 1.6235x; 1.6235x over previous
//
#include <hip/hip_runtime.h>

#define IMG_W 2048
#define NUM_NODES 255
#define NLEAF 128
#define DEPTH 7
#define RS 68   // padded LDS row stride (floats); 16B-chunk bank-group = (row+q)%8 -> balanced

// DPP xor-butterfly add over 16-lane groups (VALU pipe). Butterfly partners add
// identical pairs -> all 16 lanes end bit-identical.
template<int CTRL>
__device__ __forceinline__ float dpp_add(float x) {
    int v = __builtin_amdgcn_update_dpp(0, __float_as_int(x), CTRL, 0xF, 0xF, true);
    return x + __int_as_float(v);
}
__device__ __forceinline__ float group16_sum(float x) {
    x = dpp_add<0xB1>(x);   // quad_perm [1,0,3,2]  : xor 1
    x = dpp_add<0x4E>(x);   // quad_perm [2,3,0,1]  : xor 2
    x = dpp_add<0x141>(x);  // row_half_mirror      : xor 7
    x = dpp_add<0x128>(x);  // row_ror:8            : xor 8
    return x;
}

// ---- K1: 4-way interleaved descent (16 lanes/patch) + LDS-atomic accumulate --
// 256 blocks x 1024 thr, ~105 KB LDS -> 1 block/CU, 16 waves/CU.
// Per level: issue ALL 8 ds_read_b128 (2 per chunk), ONE wait, 4 independent
// compute blocks -> 7 latency windows per wave instead of 28.
__global__ __launch_bounds__(1024, 4) void fusedK(const float* __restrict__ img,
                                                  const float* __restrict__ nodes,
                                                  float* __restrict__ leaf_out,
                                                  float* __restrict__ S,
                                                  unsigned* __restrict__ cnt)
{
    __shared__ float nds[NUM_NODES * RS];   // 69360 B
    __shared__ float Sl[NLEAF * RS];        // 34816 B
    __shared__ unsigned cntl[NLEAF];

    const int t = threadIdx.x;
    const int b = blockIdx.x;
    const int g = t >> 4;          // patch-group 0..63
    const int q = t & 15;          // quad within patch (elements 4q..4q+3)
    const int q4 = q * 4;

    for (int i = t; i < NLEAF * RS; i += 1024) Sl[i] = 0.0f;
    if (t < NLEAF) cntl[t] = 0u;

    // fill node table (padded rows)
    const float4* ng = (const float4*)nodes;
    for (int i = t; i < NUM_NODES * 16; i += 1024) {
        *(float4*)&nds[(i >> 4) * RS + (i & 15) * 4] = ng[i];
    }

    // prefetch 4 chunks' patch quads (element e=4q+j -> pixel (q>>1, (q&1)*4+j))
    float4 xv0, xv1, xv2, xv3;
    {
        const int roff = (q >> 1), coff = (q & 1) * 4;
        int p = b * 256 + g;
        xv0 = *(const float4*)(img + (size_t)((p >> 8) * 8 + roff) * IMG_W + (p & 255) * 8 + coff);
        p += 64;
        xv1 = *(const float4*)(img + (size_t)((p >> 8) * 8 + roff) * IMG_W + (p & 255) * 8 + coff);
        p += 64;
        xv2 = *(const float4*)(img + (size_t)((p >> 8) * 8 + roff) * IMG_W + (p & 255) * 8 + coff);
        p += 64;
        xv3 = *(const float4*)(img + (size_t)((p >> 8) * 8 + roff) * IMG_W + (p & 255) * 8 + coff);
    }
    __syncthreads();

    // 4 interleaved descents
    int cur0 = 0, cur1 = 0, cur2 = 0, cur3 = 0;
    #pragma unroll
    for (int lvl = 0; lvl < DEPTH; ++lvl) {
        const int ca = 2 * cur0 + 1;
        const int cb = 2 * cur1 + 1;
        const int cc = 2 * cur2 + 1;
        const int cd = 2 * cur3 + 1;
        const float* pa = &nds[ca * RS + q4];
        const float* pb = &nds[cb * RS + q4];
        const float* pc = &nds[cc * RS + q4];
        const float* pd = &nds[cd * RS + q4];
        // issue all 8 reads; compiler batches them before one lgkmcnt wait
        const float4 A0 = *(const float4*)(pa);
        const float4 B0 = *(const float4*)(pa + RS);
        const float4 A1 = *(const float4*)(pb);
        const float4 B1 = *(const float4*)(pb + RS);
        const float4 A2 = *(const float4*)(pc);
        const float4 B2 = *(const float4*)(pc + RS);
        const float4 A3 = *(const float4*)(pd);
        const float4 B3 = *(const float4*)(pd + RS);

        float d, s0, s1;
        // chunk 0
        s0 = 0.f; s1 = 0.f;
        d = A0.x - xv0.x; s0 = fmaf(d, d, s0);  d = B0.x - xv0.x; s1 = fmaf(d, d, s1);
        d = A0.y - xv0.y; s0 = fmaf(d, d, s0);  d = B0.y - xv0.y; s1 = fmaf(d, d, s1);
        d = A0.z - xv0.z; s0 = fmaf(d, d, s0);  d = B0.z - xv0.z; s1 = fmaf(d, d, s1);
        d = A0.w - xv0.w; s0 = fmaf(d, d, s0);  d = B0.w - xv0.w; s1 = fmaf(d, d, s1);
        cur0 = (group16_sum(s1 - s0) < 0.0f) ? (ca + 1) : ca;   // d1<d0 picks c1 (strict)
        // chunk 1
        s0 = 0.f; s1 = 0.f;
        d = A1.x - xv1.x; s0 = fmaf(d, d, s0);  d = B1.x - xv1.x; s1 = fmaf(d, d, s1);
        d = A1.y - xv1.y; s0 = fmaf(d, d, s0);  d = B1.y - xv1.y; s1 = fmaf(d, d, s1);
        d = A1.z - xv1.z; s0 = fmaf(d, d, s0);  d = B1.z - xv1.z; s1 = fmaf(d, d, s1);
        d = A1.w - xv1.w; s0 = fmaf(d, d, s0);  d = B1.w - xv1.w; s1 = fmaf(d, d, s1);
        cur1 = (group16_sum(s1 - s0) < 0.0f) ? (cb + 1) : cb;
        // chunk 2
        s0 = 0.f; s1 = 0.f;
        d = A2.x - xv2.x; s0 = fmaf(d, d, s0);  d = B2.x - xv2.x; s1 = fmaf(d, d, s1);
        d = A2.y - xv2.y; s0 = fmaf(d, d, s0);  d = B2.y - xv2.y; s1 = fmaf(d, d, s1);
        d = A2.z - xv2.z; s0 = fmaf(d, d, s0);  d = B2.z - xv2.z; s1 = fmaf(d, d, s1);
        d = A2.w - xv2.w; s0 = fmaf(d, d, s0);  d = B2.w - xv2.w; s1 = fmaf(d, d, s1);
        cur2 = (group16_sum(s1 - s0) < 0.0f) ? (cc + 1) : cc;
        // chunk 3
        s0 = 0.f; s1 = 0.f;
        d = A3.x - xv3.x; s0 = fmaf(d, d, s0);  d = B3.x - xv3.x; s1 = fmaf(d, d, s1);
        d = A3.y - xv3.y; s0 = fmaf(d, d, s0);  d = B3.y - xv3.y; s1 = fmaf(d, d, s1);
        d = A3.z - xv3.z; s0 = fmaf(d, d, s0);  d = B3.z - xv3.z; s1 = fmaf(d, d, s1);
        d = A3.w - xv3.w; s0 = fmaf(d, d, s0);  d = B3.w - xv3.w; s1 = fmaf(d, d, s1);
        cur3 = (group16_sum(s1 - s0) < 0.0f) ? (cd + 1) : cd;
    }

    if (q == 0) {
        leaf_out[b * 256 + g]       = (float)cur0;
        leaf_out[b * 256 + 64 + g]  = (float)cur1;
        leaf_out[b * 256 + 128 + g] = (float)cur2;
        leaf_out[b * 256 + 192 + g] = (float)cur3;
        atomicAdd(&cntl[cur0 - 127], 1u);
        atomicAdd(&cntl[cur1 - 127], 1u);
        atomicAdd(&cntl[cur2 - 127], 1u);
        atomicAdd(&cntl[cur3 - 127], 1u);
    }

    // accumulate quads into leaf rows (R5-proven: ~2-4 us; group (L+q)%8 balanced)
    {
        float* dst = &Sl[(cur0 - 127) * RS + q4];
        atomicAdd(dst + 0, xv0.x); atomicAdd(dst + 1, xv0.y);
        atomicAdd(dst + 2, xv0.z); atomicAdd(dst + 3, xv0.w);
        dst = &Sl[(cur1 - 127) * RS + q4];
        atomicAdd(dst + 0, xv1.x); atomicAdd(dst + 1, xv1.y);
        atomicAdd(dst + 2, xv1.z); atomicAdd(dst + 3, xv1.w);
        dst = &Sl[(cur2 - 127) * RS + q4];
        atomicAdd(dst + 0, xv2.x); atomicAdd(dst + 1, xv2.y);
        atomicAdd(dst + 2, xv2.z); atomicAdd(dst + 3, xv2.w);
        dst = &Sl[(cur3 - 127) * RS + q4];
        atomicAdd(dst + 0, xv3.x); atomicAdd(dst + 1, xv3.y);
        atomicAdd(dst + 2, xv3.z); atomicAdd(dst + 3, xv3.w);
    }
    __syncthreads();

    // flush block sums to global S (skip zeros; lane-distinct addresses; S pre-zeroed)
    for (int i = t; i < NLEAF * 64; i += 1024) {
        const float v = Sl[(i >> 6) * RS + (i & 63)];
        if (v != 0.0f) atomicAdd(&S[i], v);
    }
    if (t < NLEAF && cntl[t] != 0u) atomicAdd(&cnt[t], cntl[t]);
}

// ---------------- K2: node update (254x64x128 contraction) -------------------
__global__ __launch_bounds__(256) void updateK(const float* __restrict__ nodes,
                                               const float* __restrict__ S,
                                               const unsigned* __restrict__ cnt,
                                               float* __restrict__ out)
{
    const int gid = blockIdx.x * 256 + threadIdx.x;
    if (gid >= NUM_NODES * 64) return;
    const int n = gid >> 6, k = gid & 63;
    const float nd = nodes[gid];
    if (n == 0) { out[gid] = nd; return; }

    const int pos = n + 1;                 // 1-based heap index
    const int Ln = 31 - __clz(pos);        // node level, 1..7
    float su = 0.f, sc = 0.f;
    #pragma unroll 8
    for (int L = 0; L < NLEAF; ++L) {
        const int a = (128 + L) >> (7 - Ln);   // leaf's ancestor at level Ln
        const int x = pos ^ a;
        const int state = (x == 0) ? Ln : (Ln - (31 - __clz(x)) - 1);
        const float lr = 0.3f * ((float)(1 << state) * (1.0f / 128.0f));
        su = fmaf(lr, S[L * 64 + k], su);
        sc = fmaf(lr, (float)cnt[L], sc);
    }
    const float invP = 1.0f / 65536.0f;
    out[gid] = nd + su * invP - (sc * invP) * nd;
}

extern "C" void kernel_launch(void* const* d_in, const int* in_sizes, int n_in,
                              void* d_out, int out_size, void* d_ws, size_t ws_size,
                              hipStream_t stream)
{
    const float* img   = (const float*)d_in[0];   // 2048*2048 f32
    const float* nodes = (const float*)d_in[1];   // 255*64 f32

    float* out_nodes = (float*)d_out;                 // 255*64
    float* out_leaf  = out_nodes + NUM_NODES * 64;    // 65536 (leaf index as f32)

    float*    S   = (float*)d_ws;                     // 128*64 f32
    unsigned* cnt = (unsigned*)(S + NLEAF * 64);      // 128 u32

    hipMemsetAsync(d_ws, 0, (NLEAF * 64) * sizeof(float) + NLEAF * sizeof(unsigned), stream);
    fusedK<<<256, 1024, 0, stream>>>(img, nodes, out_leaf, S, cnt);
    updateK<<<64, 256, 0, stream>>>(nodes, S, cnt, out_nodes);
}